// Round 1
// baseline (119.883 us; speedup 1.0000x reference)
//
#include <hip/hip_runtime.h>
#include <math.h>

#define UNITS 1024
#define GATES 4096  // 4*UNITS

__device__ __forceinline__ float sigmoidf(float x) { return 1.0f / (1.0f + expf(-x)); }

// ws layout (floats): [0..4095] = z0 accumulator, [4096..8191] = z1 accumulator.
// Both seeded with bias b (so z = b + x@W [+ h@U] accumulates via atomics).
__global__ __launch_bounds__(256) void k_init(const float* __restrict__ b,
                                              float* __restrict__ zacc) {
    int i = blockIdx.x * 256 + threadIdx.x;  // 0..8191
    zacc[i] = b[i & (GATES - 1)];
}

// Partial x@W for rows 0 and 1. Grid: 256 blocks = 4 column-tiles x 64 k-chunks.
// Each thread owns 4 consecutive columns (float4), loops over 16 k rows.
__global__ __launch_bounds__(256) void k_xw(const float* __restrict__ x,
                                            const float* __restrict__ W,
                                            float* __restrict__ zacc) {
    int bx = blockIdx.x;
    int jt = bx & 3;       // column tile 0..3
    int kc = bx >> 2;      // k chunk 0..63
    int j  = jt * 1024 + threadIdx.x * 4;
    int k0 = kc * 16;
    float4 a0 = make_float4(0.f, 0.f, 0.f, 0.f);
    float4 a1 = make_float4(0.f, 0.f, 0.f, 0.f);
    const float* wp = W + (size_t)k0 * GATES + j;
#pragma unroll
    for (int kk = 0; kk < 16; ++kk) {
        float x0 = x[k0 + kk];            // row 0 of inputs[0]
        float x1 = x[UNITS + k0 + kk];    // row 1 (FEAT==1024)
        float4 w = *reinterpret_cast<const float4*>(wp);
        wp += GATES;
        a0.x += x0 * w.x; a0.y += x0 * w.y; a0.z += x0 * w.z; a0.w += x0 * w.w;
        a1.x += x1 * w.x; a1.y += x1 * w.y; a1.z += x1 * w.z; a1.w += x1 * w.w;
    }
    atomicAdd(&zacc[j + 0], a0.x);
    atomicAdd(&zacc[j + 1], a0.y);
    atomicAdd(&zacc[j + 2], a0.z);
    atomicAdd(&zacc[j + 3], a0.w);
    atomicAdd(&zacc[GATES + j + 0], a1.x);
    atomicAdd(&zacc[GATES + j + 1], a1.y);
    atomicAdd(&zacc[GATES + j + 2], a1.z);
    atomicAdd(&zacc[GATES + j + 3], a1.w);
}

// Partial h0@U into z1 accumulator. h0 is recomputed on the fly from z0
// (step 0: c0 = sig(zi)*zg, h0 = sig(zo)*c0; forget gate irrelevant, c_prev=0).
__global__ __launch_bounds__(256) void k_hu(const float* __restrict__ U,
                                            float* __restrict__ zacc) {
    int bx = blockIdx.x;
    int jt = bx & 3;
    int kc = bx >> 2;
    int j  = jt * 1024 + threadIdx.x * 4;
    int k0 = kc * 16;
    __shared__ float h0s[16];
    if (threadIdx.x < 16) {
        int k = k0 + threadIdx.x;
        float zi = zacc[k];
        float zg = zacc[k + 2 * UNITS];
        float zo = zacc[k + 3 * UNITS];
        float c0 = sigmoidf(zi) * zg;
        h0s[threadIdx.x] = sigmoidf(zo) * c0;
    }
    __syncthreads();
    float4 a = make_float4(0.f, 0.f, 0.f, 0.f);
    const float* up = U + (size_t)k0 * GATES + j;
#pragma unroll
    for (int kk = 0; kk < 16; ++kk) {
        float h = h0s[kk];
        float4 w = *reinterpret_cast<const float4*>(up);
        up += GATES;
        a.x += h * w.x; a.y += h * w.y; a.z += h * w.z; a.w += h * w.w;
    }
    atomicAdd(&zacc[GATES + j + 0], a.x);
    atomicAdd(&zacc[GATES + j + 1], a.y);
    atomicAdd(&zacc[GATES + j + 2], a.z);
    atomicAdd(&zacc[GATES + j + 3], a.w);
}

// Single-block epilogue: step-1 gates, tanh, dense(2) reduction, outputs.
__global__ __launch_bounds__(1024) void k_final(const float* __restrict__ zacc,
                                                const float* __restrict__ f,
                                                const float* __restrict__ Wd,
                                                const float* __restrict__ bd,
                                                float* __restrict__ out) {
    int u = threadIdx.x;  // 0..1023
    // step 0 (recompute)
    float z0i = zacc[u];
    float z0g = zacc[u + 2 * UNITS];
    float z0o = zacc[u + 3 * UNITS];
    float c0 = sigmoidf(z0i) * z0g;
    float h0 = sigmoidf(z0o) * c0;
    // step 1
    const float* z1 = zacc + GATES;
    float z1i = z1[u];
    float z1f = z1[u + UNITS];
    float z1g = z1[u + 2 * UNITS];
    float z1o = z1[u + 3 * UNITS];
    float c1 = sigmoidf(z1f) * c0 + sigmoidf(z1i) * z1g;
    float h1 = sigmoidf(z1o) * c1;

    float n0 = tanhf(h0);
    float n1 = tanhf(h1);
    float w0 = Wd[2 * u + 0];
    float w1 = Wd[2 * u + 1];

    __shared__ float4 red[1024];
    red[u] = make_float4(n0 * w0, n0 * w1, n1 * w0, n1 * w1);
    __syncthreads();
    for (int s = 512; s > 0; s >>= 1) {
        if (u < s) {
            float4 a = red[u];
            float4 b = red[u + s];
            red[u] = make_float4(a.x + b.x, a.y + b.y, a.z + b.z, a.w + b.w);
        }
        __syncthreads();
    }
    if (u == 0) {
        float4 sacc = red[0];
        float hc00 = tanhf(sacc.x + bd[0]);
        float hc01 = tanhf(sacc.y + bd[1]);
        float hc10 = tanhf(sacc.z + bd[0]);
        float hc11 = tanhf(sacc.w + bd[1]);
        float den = f[1] - f[2];
        out[0] = hc00;
        out[1] = hc01;
        out[2] = (hc00 - hc10) / den;
        out[3] = (hc01 - hc11) / den;
    }
}

extern "C" void kernel_launch(void* const* d_in, const int* in_sizes, int n_in,
                              void* d_out, int out_size, void* d_ws, size_t ws_size,
                              hipStream_t stream) {
    const float* x  = (const float*)d_in[0];  // (1, 8192, 1024) — only rows 0,1 used
    const float* f  = (const float*)d_in[1];  // (8192, 1)
    const float* W  = (const float*)d_in[2];  // (1024, 4096)
    const float* U  = (const float*)d_in[3];  // (1024, 4096)
    const float* b  = (const float*)d_in[4];  // (4096,)
    const float* Wd = (const float*)d_in[5];  // (1024, 2)
    const float* bd = (const float*)d_in[6];  // (2,)
    float* out  = (float*)d_out;              // 4 floats
    float* zacc = (float*)d_ws;               // 8192 floats scratch

    k_init<<<32, 256, 0, stream>>>(b, zacc);
    k_xw<<<256, 256, 0, stream>>>(x, W, zacc);
    k_hu<<<256, 256, 0, stream>>>(U, zacc);
    k_final<<<1, 1024, 0, stream>>>(zacc, f, Wd, bd, out);
}

// Round 2
// 113.961 us; speedup vs baseline: 1.0520x; 1.0520x over previous
//
#include <hip/hip_runtime.h>
#include <math.h>

#define UNITS 1024
#define FEAT  1024
#define GATES 4096   // 4*UNITS
#define KC    64     // k-chunks per 1024-deep dot product
#define KROWS 16     // rows per chunk (KC*KROWS == 1024)

// ws layout (float offsets)
#define OFF_P0  0                    // x-row0 @ W partials: [KC][GATES]
#define OFF_P1  (KC*GATES)           // x-row1 @ W partials: [KC][GATES]
#define OFF_PU  (2*KC*GATES)         // h0 @ U partials:     [KC][GATES]
#define OFF_Z0  (3*KC*GATES)         // z0 = b + x0@W        [GATES]
#define OFF_Z1A (OFF_Z0 + GATES)     // z1a = b + x1@W       [GATES]
#define OFF_Z1  (OFF_Z1A + GATES)    // z1 = z1a + h0@U      [GATES]

__device__ __forceinline__ float sigmoidf(float x) { return 1.0f / (1.0f + expf(-x)); }

// K1: partial x@W for rows 0 and 1. 256 blocks = 4 col-tiles x 64 k-chunks.
// Coalesced float4 W reads, coalesced float4 partial stores. No atomics.
__global__ __launch_bounds__(256) void k_xw(const float* __restrict__ x,
                                            const float* __restrict__ W,
                                            float* __restrict__ ws) {
    int bx = blockIdx.x;
    int jt = bx & 3;       // column tile 0..3
    int kc = bx >> 2;      // k chunk 0..63
    int j  = jt * 1024 + threadIdx.x * 4;
    int k0 = kc * KROWS;
    float4 a0 = make_float4(0.f, 0.f, 0.f, 0.f);
    float4 a1 = make_float4(0.f, 0.f, 0.f, 0.f);
    const float* wp = W + (size_t)k0 * GATES + j;
#pragma unroll
    for (int kk = 0; kk < KROWS; ++kk) {
        float x0 = x[k0 + kk];          // inputs row 0
        float x1 = x[FEAT + k0 + kk];   // inputs row 1
        float4 w = *reinterpret_cast<const float4*>(wp);
        wp += GATES;
        a0.x += x0 * w.x; a0.y += x0 * w.y; a0.z += x0 * w.z; a0.w += x0 * w.w;
        a1.x += x1 * w.x; a1.y += x1 * w.y; a1.z += x1 * w.z; a1.w += x1 * w.w;
    }
    *reinterpret_cast<float4*>(&ws[OFF_P0 + kc * GATES + j]) = a0;
    *reinterpret_cast<float4*>(&ws[OFF_P1 + kc * GATES + j]) = a1;
}

// K2: reduce P0,P1 over k-chunks, add bias -> Z0[4096], Z1A[4096] (contiguous).
// 32 blocks x 256 threads, one column per thread, coalesced reads.
__global__ __launch_bounds__(256) void k_red1(const float* __restrict__ b,
                                              float* __restrict__ ws) {
    int i = blockIdx.x * 256 + threadIdx.x;   // 0..8191
    int c = i & (GATES - 1);
    const float* P = ws + (i < GATES ? OFF_P0 : OFF_P1);
    float s = b[c];
#pragma unroll 8
    for (int kc = 0; kc < KC; ++kc) s += P[kc * GATES + c];
    ws[OFF_Z0 + i] = s;   // Z1A immediately follows Z0
}

// K3: partial h0@U. h0 recomputed from Z0 (step 0: c0=sig(zi)*zg, h0=sig(zo)*c0).
__global__ __launch_bounds__(256) void k_hu(const float* __restrict__ U,
                                            float* __restrict__ ws) {
    int bx = blockIdx.x;
    int jt = bx & 3;
    int kc = bx >> 2;
    int j  = jt * 1024 + threadIdx.x * 4;
    int k0 = kc * KROWS;
    __shared__ float h0s[KROWS];
    if (threadIdx.x < KROWS) {
        const float* Z0 = ws + OFF_Z0;
        int k = k0 + threadIdx.x;
        float c0 = sigmoidf(Z0[k]) * Z0[k + 2 * UNITS];
        h0s[threadIdx.x] = sigmoidf(Z0[k + 3 * UNITS]) * c0;
    }
    __syncthreads();
    float4 a = make_float4(0.f, 0.f, 0.f, 0.f);
    const float* up = U + (size_t)k0 * GATES + j;
#pragma unroll
    for (int kk = 0; kk < KROWS; ++kk) {
        float h = h0s[kk];
        float4 w = *reinterpret_cast<const float4*>(up);
        up += GATES;
        a.x += h * w.x; a.y += h * w.y; a.z += h * w.z; a.w += h * w.w;
    }
    *reinterpret_cast<float4*>(&ws[OFF_PU + kc * GATES + j]) = a;
}

// K4: reduce PU over k-chunks, add Z1A -> Z1[4096]. 16 blocks x 256 threads.
__global__ __launch_bounds__(256) void k_red2(float* __restrict__ ws) {
    int c = blockIdx.x * 256 + threadIdx.x;   // 0..4095
    float s = ws[OFF_Z1A + c];
    const float* PU = ws + OFF_PU;
#pragma unroll 8
    for (int kc = 0; kc < KC; ++kc) s += PU[kc * GATES + c];
    ws[OFF_Z1 + c] = s;
}

// K5: step-1 gates, tanh, dense(2) reduction, outputs. 1 block x 1024.
__global__ __launch_bounds__(1024) void k_final(const float* __restrict__ ws,
                                                const float* __restrict__ f,
                                                const float* __restrict__ Wd,
                                                const float* __restrict__ bd,
                                                float* __restrict__ out) {
    int u = threadIdx.x;  // 0..1023
    const float* Z0 = ws + OFF_Z0;
    const float* Z1 = ws + OFF_Z1;
    float c0 = sigmoidf(Z0[u]) * Z0[u + 2 * UNITS];
    float h0 = sigmoidf(Z0[u + 3 * UNITS]) * c0;
    float c1 = sigmoidf(Z1[u + UNITS]) * c0 + sigmoidf(Z1[u]) * Z1[u + 2 * UNITS];
    float h1 = sigmoidf(Z1[u + 3 * UNITS]) * c1;

    float n0 = tanhf(h0);
    float n1 = tanhf(h1);
    float w0 = Wd[2 * u + 0];
    float w1 = Wd[2 * u + 1];

    __shared__ float4 red[1024];
    red[u] = make_float4(n0 * w0, n0 * w1, n1 * w0, n1 * w1);
    __syncthreads();
    for (int s = 512; s > 0; s >>= 1) {
        if (u < s) {
            float4 a = red[u];
            float4 b = red[u + s];
            red[u] = make_float4(a.x + b.x, a.y + b.y, a.z + b.z, a.w + b.w);
        }
        __syncthreads();
    }
    if (u == 0) {
        float4 sa = red[0];
        float hc00 = tanhf(sa.x + bd[0]);
        float hc01 = tanhf(sa.y + bd[1]);
        float hc10 = tanhf(sa.z + bd[0]);
        float hc11 = tanhf(sa.w + bd[1]);
        float den = f[1] - f[2];
        out[0] = hc00;
        out[1] = hc01;
        out[2] = (hc00 - hc10) / den;
        out[3] = (hc01 - hc11) / den;
    }
}

extern "C" void kernel_launch(void* const* d_in, const int* in_sizes, int n_in,
                              void* d_out, int out_size, void* d_ws, size_t ws_size,
                              hipStream_t stream) {
    const float* x  = (const float*)d_in[0];  // (1, 8192, 1024) — only rows 0,1 used
    const float* f  = (const float*)d_in[1];  // (8192, 1)
    const float* W  = (const float*)d_in[2];  // (1024, 4096)
    const float* U  = (const float*)d_in[3];  // (1024, 4096)
    const float* b  = (const float*)d_in[4];  // (4096,)
    const float* Wd = (const float*)d_in[5];  // (1024, 2)
    const float* bd = (const float*)d_in[6];  // (2,)
    float* out = (float*)d_out;               // 4 floats
    float* ws  = (float*)d_ws;                // ~3.1 MB scratch used

    k_xw  <<<256, 256, 0, stream>>>(x, W, ws);
    k_red1<<< 32, 256, 0, stream>>>(b, ws);
    k_hu  <<<256, 256, 0, stream>>>(U, ws);
    k_red2<<< 16, 256, 0, stream>>>(ws);
    k_final<<< 1, 1024, 0, stream>>>(ws, f, Wd, bd, out);
}

// Round 3
// 110.509 us; speedup vs baseline: 1.0848x; 1.0312x over previous
//
#include <hip/hip_runtime.h>
#include <math.h>

#define UNITS 1024
#define FEAT  1024
#define GATES 4096   // 4*UNITS
#define KC    64     // k-chunks per 1024-deep dot product
#define KROWS 16     // rows per chunk (KC*KROWS == 1024)

// ws layout (float offsets)
#define OFF_P0  0                    // x-row0 @ W partials: [KC][GATES]
#define OFF_P1  (KC*GATES)           // x-row1 @ W partials: [KC][GATES]
#define OFF_PU  (2*KC*GATES)         // h0 @ U partials:     [KC][GATES]
#define OFF_Z0  (3*KC*GATES)         // z0 = b + x0@W        [GATES]
#define OFF_Z1  (OFF_Z0 + GATES)     // z1 = b + x1@W + h0@U [GATES]

__device__ __forceinline__ float sigmoidf(float x) { return 1.0f / (1.0f + expf(-x)); }

// K1: partial x@W for rows 0 and 1. 256 blocks = 4 col-tiles x 64 k-chunks.
__global__ __launch_bounds__(256) void k_xw(const float* __restrict__ x,
                                            const float* __restrict__ W,
                                            float* __restrict__ ws) {
    int bx = blockIdx.x;
    int jt = bx & 3;       // column tile 0..3
    int kc = bx >> 2;      // k chunk 0..63
    int j  = jt * 1024 + threadIdx.x * 4;
    int k0 = kc * KROWS;
    float4 a0 = make_float4(0.f, 0.f, 0.f, 0.f);
    float4 a1 = make_float4(0.f, 0.f, 0.f, 0.f);
    const float* wp = W + (size_t)k0 * GATES + j;
#pragma unroll
    for (int kk = 0; kk < KROWS; ++kk) {
        float x0 = x[k0 + kk];          // inputs row 0 (block-uniform -> SMEM)
        float x1 = x[FEAT + k0 + kk];   // inputs row 1
        float4 w = *reinterpret_cast<const float4*>(wp);
        wp += GATES;
        a0.x += x0 * w.x; a0.y += x0 * w.y; a0.z += x0 * w.z; a0.w += x0 * w.w;
        a1.x += x1 * w.x; a1.y += x1 * w.y; a1.z += x1 * w.z; a1.w += x1 * w.w;
    }
    *reinterpret_cast<float4*>(&ws[OFF_P0 + kc * GATES + j]) = a0;
    *reinterpret_cast<float4*>(&ws[OFF_P1 + kc * GATES + j]) = a1;
}

// K2: partial h0@U, with the z0 reduction for this block's 16 h0 entries done
// inline (48 z0 columns: i-gate k, c-gate k+2048, o-gate k+3072; 64 partials
// each). U tile is prefetched into registers first so its HBM latency overlaps
// the reduction. No separate k_red1 dispatch.
__global__ __launch_bounds__(256) void k_hu(const float* __restrict__ U,
                                            const float* __restrict__ b,
                                            float* __restrict__ ws) {
    int bx = blockIdx.x;
    int jt = bx & 3;
    int kc = bx >> 2;
    int tid = threadIdx.x;
    int j  = jt * 1024 + tid * 4;
    int k0 = kc * KROWS;

    // --- prefetch U tile into registers (independent of the z0 reduction) ---
    float4 ureg[KROWS];
    {
        const float* up = U + (size_t)k0 * GATES + j;
#pragma unroll
        for (int kk = 0; kk < KROWS; ++kk) {
            ureg[kk] = *reinterpret_cast<const float4*>(up);
            up += GATES;
        }
    }

    // --- inline z0 reduction for the 48 needed columns ---
    // col_idx 0..15 -> zi (offset 0), 16..31 -> zg (+2048), 32..47 -> zo (+3072)
    __shared__ float zred[48][4];
    __shared__ float zcol[48];
    __shared__ float h0s[KROWS];
    if (tid < 192) {
        int col_idx = tid >> 2;     // 0..47
        int part    = tid & 3;      // 0..3 (16 partials each)
        int sel     = col_idx >> 4; // 0,1,2
        int off     = (sel == 0) ? 0 : (sel == 1 ? 2 * UNITS : 3 * UNITS);
        int col     = off + k0 + (col_idx & 15);
        const float* P0 = ws + OFF_P0;
        float s = 0.f;
#pragma unroll
        for (int kcc = part * 16; kcc < part * 16 + 16; ++kcc)
            s += P0[kcc * GATES + col];
        zred[col_idx][part] = s;
    }
    __syncthreads();
    if (tid < 48) {
        int sel = tid >> 4;
        int off = (sel == 0) ? 0 : (sel == 1 ? 2 * UNITS : 3 * UNITS);
        int col = off + k0 + (tid & 15);
        zcol[tid] = zred[tid][0] + zred[tid][1] + zred[tid][2] + zred[tid][3] + b[col];
    }
    __syncthreads();
    if (tid < KROWS) {
        float c0 = sigmoidf(zcol[tid]) * zcol[tid + 16];
        h0s[tid] = sigmoidf(zcol[tid + 32]) * c0;
    }
    __syncthreads();

    // --- h0 @ U partial ---
    float4 a = make_float4(0.f, 0.f, 0.f, 0.f);
#pragma unroll
    for (int kk = 0; kk < KROWS; ++kk) {
        float h = h0s[kk];
        a.x += h * ureg[kk].x; a.y += h * ureg[kk].y;
        a.z += h * ureg[kk].z; a.w += h * ureg[kk].w;
    }
    *reinterpret_cast<float4*>(&ws[OFF_PU + kc * GATES + j]) = a;
}

// K3: final reductions. 32 blocks x 256. Blocks 0..15 -> Z1 (b + P1 + PU),
// blocks 16..31 -> Z0 (b + P0). Coalesced scalar column reads.
__global__ __launch_bounds__(256) void k_red(const float* __restrict__ b,
                                             float* __restrict__ ws) {
    int i = blockIdx.x * 256 + threadIdx.x;   // 0..8191
    if (i < GATES) {
        int c = i;
        float s = b[c];
        const float* P1 = ws + OFF_P1;
        const float* PU = ws + OFF_PU;
#pragma unroll 8
        for (int kc = 0; kc < KC; ++kc) s += P1[kc * GATES + c] + PU[kc * GATES + c];
        ws[OFF_Z1 + c] = s;
    } else {
        int c = i - GATES;
        float s = b[c];
        const float* P0 = ws + OFF_P0;
#pragma unroll 8
        for (int kc = 0; kc < KC; ++kc) s += P0[kc * GATES + c];
        ws[OFF_Z0 + c] = s;
    }
}

// K4: step-0/1 gates, tanh, dense(2) reduction (shfl + 1 LDS hop), outputs.
__global__ __launch_bounds__(1024) void k_final(const float* __restrict__ ws,
                                                const float* __restrict__ f,
                                                const float* __restrict__ Wd,
                                                const float* __restrict__ bd,
                                                float* __restrict__ out) {
    int u = threadIdx.x;  // 0..1023
    const float* Z0 = ws + OFF_Z0;
    const float* Z1 = ws + OFF_Z1;
    float c0 = sigmoidf(Z0[u]) * Z0[u + 2 * UNITS];
    float h0 = sigmoidf(Z0[u + 3 * UNITS]) * c0;
    float c1 = sigmoidf(Z1[u + UNITS]) * c0 + sigmoidf(Z1[u]) * Z1[u + 2 * UNITS];
    float h1 = sigmoidf(Z1[u + 3 * UNITS]) * c1;

    float n0 = tanhf(h0);
    float n1 = tanhf(h1);
    float2 wd = *reinterpret_cast<const float2*>(&Wd[2 * u]);

    float4 v = make_float4(n0 * wd.x, n0 * wd.y, n1 * wd.x, n1 * wd.y);
    // wave-64 shuffle reduction
#pragma unroll
    for (int s = 32; s > 0; s >>= 1) {
        v.x += __shfl_down(v.x, s);
        v.y += __shfl_down(v.y, s);
        v.z += __shfl_down(v.z, s);
        v.w += __shfl_down(v.w, s);
    }
    __shared__ float4 wred[16];
    int wave = u >> 6;
    if ((u & 63) == 0) wred[wave] = v;
    __syncthreads();
    if (u == 0) {
        float4 sa = wred[0];
#pragma unroll
        for (int w = 1; w < 16; ++w) {
            float4 t = wred[w];
            sa.x += t.x; sa.y += t.y; sa.z += t.z; sa.w += t.w;
        }
        float hc00 = tanhf(sa.x + bd[0]);
        float hc01 = tanhf(sa.y + bd[1]);
        float hc10 = tanhf(sa.z + bd[0]);
        float hc11 = tanhf(sa.w + bd[1]);
        float den = f[1] - f[2];
        out[0] = hc00;
        out[1] = hc01;
        out[2] = (hc00 - hc10) / den;
        out[3] = (hc01 - hc11) / den;
    }
}

extern "C" void kernel_launch(void* const* d_in, const int* in_sizes, int n_in,
                              void* d_out, int out_size, void* d_ws, size_t ws_size,
                              hipStream_t stream) {
    const float* x  = (const float*)d_in[0];  // (1, 8192, 1024) — only rows 0,1 used
    const float* f  = (const float*)d_in[1];  // (8192, 1)
    const float* W  = (const float*)d_in[2];  // (1024, 4096)
    const float* U  = (const float*)d_in[3];  // (1024, 4096)
    const float* b  = (const float*)d_in[4];  // (4096,)
    const float* Wd = (const float*)d_in[5];  // (1024, 2)
    const float* bd = (const float*)d_in[6];  // (2,)
    float* out = (float*)d_out;               // 4 floats
    float* ws  = (float*)d_ws;                // ~3.2 MB scratch used

    k_xw   <<<256, 256, 0, stream>>>(x, W, ws);
    k_hu   <<<256, 256, 0, stream>>>(U, b, ws);
    k_red  <<< 32, 256, 0, stream>>>(b, ws);
    k_final<<<  1, 1024, 0, stream>>>(ws, f, Wd, bd, out);
}

// Round 4
// 105.798 us; speedup vs baseline: 1.1331x; 1.0445x over previous
//
#include <hip/hip_runtime.h>
#include <math.h>

#define UNITS 1024
#define FEAT  1024
#define GATES 4096   // 4*UNITS

// ws layout (float offsets) — no partials, just the three 4096-vectors
#define OFF_Z0  0                 // z0  = b + x0@W
#define OFF_Z1X (GATES)           // z1x = b + x1@W
#define OFF_Z1  (2*GATES)         // z1  = z1x + h0@U

__device__ __forceinline__ float sigmoidf(float x) { return 1.0f / (1.0f + expf(-x)); }

// Column-group for a block: XCD-aware swizzle (bx%8 = XCD heuristic) so each
// XCD owns 32 consecutive 16-col groups = 512 contiguous columns -> its 64 B
// wave segments pair up inside the same XCD's L2 lines.
__device__ __forceinline__ int col_group(int bx) {
    return ((bx & 7) << 5) + (bx >> 3);
}

// K1: 256 blocks, each computes 16 full-depth columns of BOTH x0@W and x1@W,
// writing z0 and z1x directly. W read exactly once, no partials.
// Thread map: q = tid&3 -> 4-col quad (float4), rowbase = tid>>2 (64 rows/pass).
__global__ __launch_bounds__(256) void k_xw(const float* __restrict__ x,
                                            const float* __restrict__ W,
                                            const float* __restrict__ b,
                                            float* __restrict__ ws) {
    int tid = threadIdx.x;
    int c0 = col_group(blockIdx.x) * 16;

    __shared__ float xs0[FEAT], xs1[FEAT];
    {
        float4 v0 = *reinterpret_cast<const float4*>(&x[tid * 4]);
        float4 v1 = *reinterpret_cast<const float4*>(&x[FEAT + tid * 4]);
        *reinterpret_cast<float4*>(&xs0[tid * 4]) = v0;
        *reinterpret_cast<float4*>(&xs1[tid * 4]) = v1;
    }
    __syncthreads();

    int q = tid & 3;
    int rowbase = tid >> 2;           // 0..63
    const float* wp = W + (size_t)rowbase * GATES + c0 + q * 4;
    float4 a0 = make_float4(0.f, 0.f, 0.f, 0.f);
    float4 a1 = make_float4(0.f, 0.f, 0.f, 0.f);
#pragma unroll
    for (int it = 0; it < 16; ++it) {
        int row = it * 64 + rowbase;
        float4 w = *reinterpret_cast<const float4*>(wp + (size_t)it * 64 * GATES);
        float x0 = xs0[row], x1 = xs1[row];
        a0.x += x0 * w.x; a0.y += x0 * w.y; a0.z += x0 * w.z; a0.w += x0 * w.w;
        a1.x += x1 * w.x; a1.y += x1 * w.y; a1.z += x1 * w.z; a1.w += x1 * w.w;
    }
    // reduce across rowbase (stride-4 lanes share q)
#pragma unroll
    for (int s = 32; s >= 4; s >>= 1) {
        a0.x += __shfl_down(a0.x, s); a0.y += __shfl_down(a0.y, s);
        a0.z += __shfl_down(a0.z, s); a0.w += __shfl_down(a0.w, s);
        a1.x += __shfl_down(a1.x, s); a1.y += __shfl_down(a1.y, s);
        a1.z += __shfl_down(a1.z, s); a1.w += __shfl_down(a1.w, s);
    }
    __shared__ float4 p0[4][4], p1[4][4];   // [wave][q]
    int wave = tid >> 6, lane = tid & 63;
    if (lane < 4) { p0[wave][lane] = a0; p1[wave][lane] = a1; }
    __syncthreads();
    if (tid < 4) {
        float4 s0 = p0[0][tid], s1 = p1[0][tid];
#pragma unroll
        for (int w = 1; w < 4; ++w) {
            s0.x += p0[w][tid].x; s0.y += p0[w][tid].y; s0.z += p0[w][tid].z; s0.w += p0[w][tid].w;
            s1.x += p1[w][tid].x; s1.y += p1[w][tid].y; s1.z += p1[w][tid].z; s1.w += p1[w][tid].w;
        }
        float4 bb = *reinterpret_cast<const float4*>(&b[c0 + tid * 4]);
        s0.x += bb.x; s0.y += bb.y; s0.z += bb.z; s0.w += bb.w;
        s1.x += bb.x; s1.y += bb.y; s1.z += bb.z; s1.w += bb.w;
        *reinterpret_cast<float4*>(&ws[OFF_Z0 + c0 + tid * 4]) = s0;
        *reinterpret_cast<float4*>(&ws[OFF_Z1X + c0 + tid * 4]) = s1;
    }
}

// K2: 256 blocks, each recomputes all 1024 h0 from z0 (12 KB, L2-hot) into LDS,
// then computes 16 full-depth columns of h0@U and writes z1 = z1x + that.
__global__ __launch_bounds__(256) void k_hu(const float* __restrict__ U,
                                            float* __restrict__ ws) {
    int tid = threadIdx.x;
    int c0 = col_group(blockIdx.x) * 16;

    __shared__ float h0s[UNITS];
    {
        int u0 = tid * 4;
        float4 zi = *reinterpret_cast<const float4*>(&ws[OFF_Z0 + u0]);
        float4 zg = *reinterpret_cast<const float4*>(&ws[OFF_Z0 + 2 * UNITS + u0]);
        float4 zo = *reinterpret_cast<const float4*>(&ws[OFF_Z0 + 3 * UNITS + u0]);
        float4 h;
        h.x = sigmoidf(zo.x) * (sigmoidf(zi.x) * zg.x);
        h.y = sigmoidf(zo.y) * (sigmoidf(zi.y) * zg.y);
        h.z = sigmoidf(zo.z) * (sigmoidf(zi.z) * zg.z);
        h.w = sigmoidf(zo.w) * (sigmoidf(zi.w) * zg.w);
        *reinterpret_cast<float4*>(&h0s[u0]) = h;
    }
    __syncthreads();

    int q = tid & 3;
    int rowbase = tid >> 2;
    const float* up = U + (size_t)rowbase * GATES + c0 + q * 4;
    float4 a = make_float4(0.f, 0.f, 0.f, 0.f);
#pragma unroll
    for (int it = 0; it < 16; ++it) {
        int row = it * 64 + rowbase;
        float4 u4 = *reinterpret_cast<const float4*>(up + (size_t)it * 64 * GATES);
        float h = h0s[row];
        a.x += h * u4.x; a.y += h * u4.y; a.z += h * u4.z; a.w += h * u4.w;
    }
#pragma unroll
    for (int s = 32; s >= 4; s >>= 1) {
        a.x += __shfl_down(a.x, s); a.y += __shfl_down(a.y, s);
        a.z += __shfl_down(a.z, s); a.w += __shfl_down(a.w, s);
    }
    __shared__ float4 pu[4][4];
    int wave = tid >> 6, lane = tid & 63;
    if (lane < 4) pu[wave][lane] = a;
    __syncthreads();
    if (tid < 4) {
        float4 s = pu[0][tid];
#pragma unroll
        for (int w = 1; w < 4; ++w) {
            s.x += pu[w][tid].x; s.y += pu[w][tid].y; s.z += pu[w][tid].z; s.w += pu[w][tid].w;
        }
        float4 zx = *reinterpret_cast<const float4*>(&ws[OFF_Z1X + c0 + tid * 4]);
        s.x += zx.x; s.y += zx.y; s.z += zx.z; s.w += zx.w;
        *reinterpret_cast<float4*>(&ws[OFF_Z1 + c0 + tid * 4]) = s;
    }
}

// K3: gates for steps 0/1, tanh, dense(2) reduction, outputs. 1 block x 1024.
__global__ __launch_bounds__(1024) void k_final(const float* __restrict__ ws,
                                                const float* __restrict__ f,
                                                const float* __restrict__ Wd,
                                                const float* __restrict__ bd,
                                                float* __restrict__ out) {
    int u = threadIdx.x;  // 0..1023
    const float* Z0 = ws + OFF_Z0;
    const float* Z1 = ws + OFF_Z1;
    float c0 = sigmoidf(Z0[u]) * Z0[u + 2 * UNITS];
    float h0 = sigmoidf(Z0[u + 3 * UNITS]) * c0;
    float c1 = sigmoidf(Z1[u + UNITS]) * c0 + sigmoidf(Z1[u]) * Z1[u + 2 * UNITS];
    float h1 = sigmoidf(Z1[u + 3 * UNITS]) * c1;

    float n0 = tanhf(h0);
    float n1 = tanhf(h1);
    float2 wd = *reinterpret_cast<const float2*>(&Wd[2 * u]);

    float4 v = make_float4(n0 * wd.x, n0 * wd.y, n1 * wd.x, n1 * wd.y);
#pragma unroll
    for (int s = 32; s > 0; s >>= 1) {
        v.x += __shfl_down(v.x, s);
        v.y += __shfl_down(v.y, s);
        v.z += __shfl_down(v.z, s);
        v.w += __shfl_down(v.w, s);
    }
    __shared__ float4 wred[16];
    int wave = u >> 6;
    if ((u & 63) == 0) wred[wave] = v;
    __syncthreads();
    if (u == 0) {
        float4 sa = wred[0];
#pragma unroll
        for (int w = 1; w < 16; ++w) {
            float4 t = wred[w];
            sa.x += t.x; sa.y += t.y; sa.z += t.z; sa.w += t.w;
        }
        float hc00 = tanhf(sa.x + bd[0]);
        float hc01 = tanhf(sa.y + bd[1]);
        float hc10 = tanhf(sa.z + bd[0]);
        float hc11 = tanhf(sa.w + bd[1]);
        float den = f[1] - f[2];
        out[0] = hc00;
        out[1] = hc01;
        out[2] = (hc00 - hc10) / den;
        out[3] = (hc01 - hc11) / den;
    }
}

extern "C" void kernel_launch(void* const* d_in, const int* in_sizes, int n_in,
                              void* d_out, int out_size, void* d_ws, size_t ws_size,
                              hipStream_t stream) {
    const float* x  = (const float*)d_in[0];  // (1, 8192, 1024) — only rows 0,1 used
    const float* f  = (const float*)d_in[1];  // (8192, 1)
    const float* W  = (const float*)d_in[2];  // (1024, 4096)
    const float* U  = (const float*)d_in[3];  // (1024, 4096)
    const float* b  = (const float*)d_in[4];  // (4096,)
    const float* Wd = (const float*)d_in[5];  // (1024, 2)
    const float* bd = (const float*)d_in[6];  // (2,)
    float* out = (float*)d_out;               // 4 floats
    float* ws  = (float*)d_ws;                // 48 KB scratch used

    k_xw   <<<256, 256, 0, stream>>>(x, W, b, ws);
    k_hu   <<<256, 256, 0, stream>>>(U, ws);
    k_final<<<  1, 1024, 0, stream>>>(ws, f, Wd, bd, out);
}